// Round 32
// baseline (126.252 us; speedup 1.0000x reference)
//
#include <hip/hip_runtime.h>
#include <math.h>

#define NHEADS 8
#define DHEAD 64
#define NDIM 512
#define NFREQ 32
#define POSD 130           // 2*(32*2+1)
#define NB 2
#define NL 272
#define NLS 256
#define NROWS (NB*NL)      // 544
#define ATTN_SCALE 0.125f
#define PHYS_SCALE 51.5f
#define PI_F 3.14159265358979323846f
#define USTR 168           // u_s row stride (shorts)
#define PSTR 72            // p_bf row stride (shorts)
#define PTSTR 72           // pe_t row stride (shorts), 144B, 16B-aligned
#define PART_STRIDE 264    // 256 o + 4 m + 4 l
#define SROWS 320          // padded rows per (head,batch)
#define SCOLS 320          // padded key cols
#define UCOLS 132

typedef short s16x8 __attribute__((ext_vector_type(8)));
typedef float f32x4 __attribute__((ext_vector_type(4)));

__device__ __forceinline__ short bfb(float x) {
  unsigned short u = __builtin_bit_cast(unsigned short, (__bf16)x);
  return (short)u;
}

// ---------------------------------------------------------------------------
// K1: qkv = x @ [Wq | Wk[:512] | Wv[:512]]   (M=544, N=1536, K=512, fp32)
// ---------------------------------------------------------------------------
__global__ __launch_bounds__(256) void qkv_gemm_k(
    const float* __restrict__ x,
    const float* __restrict__ Wq, const float* __restrict__ Wk,
    const float* __restrict__ Wv,
    float* __restrict__ qkv)
{
  __shared__ float As[16][68];
  __shared__ float Bs[16][64];
  const int t  = threadIdx.x;
  const int m0 = blockIdx.x * 64;
  const int ng = blockIdx.y * 64;
  const int region = ng >> 9;
  const int n0 = ng & 511;
  const float* W = (region == 0) ? Wq : (region == 1) ? Wk : Wv;
  float* out = qkv + (size_t)region * (NROWS * NDIM);

  const int tx = t & 15, ty = t >> 4;
  const int arow = t >> 2, akq = (t & 3) * 4;
  const int brow = t >> 4, bcol = (t & 15) * 4;

  float acc[4][4];
#pragma unroll
  for (int i = 0; i < 4; ++i)
#pragma unroll
    for (int j = 0; j < 4; ++j) acc[i][j] = 0.f;

  for (int k0 = 0; k0 < 512; k0 += 16) {
    float4 av = make_float4(0.f, 0.f, 0.f, 0.f);
    if (m0 + arow < NROWS)
      av = *(const float4*)&x[(size_t)(m0 + arow) * NDIM + k0 + akq];
    As[akq + 0][arow] = av.x; As[akq + 1][arow] = av.y;
    As[akq + 2][arow] = av.z; As[akq + 3][arow] = av.w;
    *(float4*)&Bs[brow][bcol] =
        *(const float4*)&W[(size_t)(k0 + brow) * NDIM + n0 + bcol];
    __syncthreads();
#pragma unroll
    for (int kk = 0; kk < 16; ++kk) {
      float4 a = *(const float4*)&As[kk][ty * 4];
      float4 b = *(const float4*)&Bs[kk][tx * 4];
      float aa[4] = {a.x, a.y, a.z, a.w};
      float bb[4] = {b.x, b.y, b.z, b.w};
#pragma unroll
      for (int i = 0; i < 4; ++i)
#pragma unroll
        for (int j = 0; j < 4; ++j) acc[i][j] = fmaf(aa[i], bb[j], acc[i][j]);
    }
    __syncthreads();
  }
#pragma unroll
  for (int i = 0; i < 4; ++i) {
    int row = m0 + ty * 4 + i;
    if (row < NROWS)
      *(float4*)&out[(size_t)row * NDIM + n0 + tx * 4] =
          make_float4(acc[i][0], acc[i][1], acc[i][2], acc[i][3]);
  }
}

// ---------------------------------------------------------------------------
// K2: S[h,b,i,j] = scale * q_i(h).k_j(h)  (j<272) ; U[h,b,i,f] = q_i(h).Wk_pe_f(h)
// ---------------------------------------------------------------------------
__global__ __launch_bounds__(256) void su_gemm_k(
    const float* __restrict__ qb, const float* __restrict__ kb,
    const float* __restrict__ Wk,
    float* __restrict__ s_ws, short* __restrict__ u_ws)
{
  __shared__ float As[16][68];
  __shared__ float Bs[16][68];
  const int t = threadIdx.x;
  const int bx = blockIdx.x;
  const int b = bx / 5;
  const int m0 = (bx - b * 5) * 64;
  const int nt = blockIdx.y;
  const int h = blockIdx.z;
  const int n0 = nt * 64;

  const int tx = t & 15, ty = t >> 4;
  const int arow = t >> 2, akq = (t & 3) * 4;

  float acc[4][4];
#pragma unroll
  for (int i = 0; i < 4; ++i)
#pragma unroll
    for (int j = 0; j < 4; ++j) acc[i][j] = 0.f;

  for (int k0 = 0; k0 < 64; k0 += 16) {
    float4 av = make_float4(0.f, 0.f, 0.f, 0.f);
    {
      int i = m0 + arow;
      if (i < NL)
        av = *(const float4*)&qb[(size_t)(b * NL + i) * NDIM + h * DHEAD + k0 + akq];
    }
    As[akq + 0][arow] = av.x; As[akq + 1][arow] = av.y;
    As[akq + 2][arow] = av.z; As[akq + 3][arow] = av.w;
    float4 bv = make_float4(0.f, 0.f, 0.f, 0.f);
    if (nt < 5) {
      int j = n0 + arow;
      if (j < NL)
        bv = *(const float4*)&kb[(size_t)(b * NL + j) * NDIM + h * DHEAD + k0 + akq];
    } else {
      int f = n0 - 320 + arow;
      if (f < POSD)
        bv = *(const float4*)&Wk[(size_t)(512 + f) * NDIM + h * DHEAD + k0 + akq];
    }
    Bs[akq + 0][arow] = bv.x; Bs[akq + 1][arow] = bv.y;
    Bs[akq + 2][arow] = bv.z; Bs[akq + 3][arow] = bv.w;
    __syncthreads();
#pragma unroll
    for (int kk = 0; kk < 16; ++kk) {
      float4 a = *(const float4*)&As[kk][ty * 4];
      float4 b2 = *(const float4*)&Bs[kk][tx * 4];
      float aa[4] = {a.x, a.y, a.z, a.w};
      float bb[4] = {b2.x, b2.y, b2.z, b2.w};
#pragma unroll
      for (int i = 0; i < 4; ++i)
#pragma unroll
        for (int j = 0; j < 4; ++j) acc[i][j] = fmaf(aa[i], bb[j], acc[i][j]);
    }
    __syncthreads();
  }

  const size_t rowbase = (size_t)((h * NB + b) * SROWS + m0);
  if (nt < 5) {
#pragma unroll
    for (int ii = 0; ii < 4; ++ii) {
      size_t r = rowbase + ty * 4 + ii;
      *(float4*)&s_ws[r * SCOLS + n0 + tx * 4] =
          make_float4(acc[ii][0] * ATTN_SCALE, acc[ii][1] * ATTN_SCALE,
                      acc[ii][2] * ATTN_SCALE, acc[ii][3] * ATTN_SCALE);
    }
  } else {
#pragma unroll
    for (int ii = 0; ii < 4; ++ii) {
      size_t r = rowbase + ty * 4 + ii;
#pragma unroll
      for (int jj = 0; jj < 4; ++jj) {
        int f = n0 - 320 + tx * 4 + jj;
        if (f < POSD) u_ws[r * UCOLS + f] = bfb(acc[ii][jj]);
      }
    }
  }
}

// ---------------------------------------------------------------------------
// K5: out = attn_out @ Wo + bo
// ---------------------------------------------------------------------------
__global__ __launch_bounds__(256) void out_gemm_k(
    const float* __restrict__ A, const float* __restrict__ Wo,
    const float* __restrict__ bo, float* __restrict__ out)
{
  __shared__ float As[16][68];
  __shared__ float Bs[16][64];
  const int t  = threadIdx.x;
  const int m0 = blockIdx.x * 64;
  const int n0 = blockIdx.y * 64;

  const int tx = t & 15, ty = t >> 4;
  const int arow = t >> 2, akq = (t & 3) * 4;
  const int brow = t >> 4, bcol = (t & 15) * 4;

  float acc[4][4];
#pragma unroll
  for (int i = 0; i < 4; ++i)
#pragma unroll
    for (int j = 0; j < 4; ++j) acc[i][j] = 0.f;

  for (int k0 = 0; k0 < 512; k0 += 16) {
    float4 av = make_float4(0.f, 0.f, 0.f, 0.f);
    if (m0 + arow < NROWS)
      av = *(const float4*)&A[(size_t)(m0 + arow) * NDIM + k0 + akq];
    As[akq + 0][arow] = av.x; As[akq + 1][arow] = av.y;
    As[akq + 2][arow] = av.z; As[akq + 3][arow] = av.w;
    *(float4*)&Bs[brow][bcol] =
        *(const float4*)&Wo[(size_t)(k0 + brow) * NDIM + n0 + bcol];
    __syncthreads();
#pragma unroll
    for (int kk = 0; kk < 16; ++kk) {
      float4 a = *(const float4*)&As[kk][ty * 4];
      float4 b = *(const float4*)&Bs[kk][tx * 4];
      float aa[4] = {a.x, a.y, a.z, a.w};
      float bb[4] = {b.x, b.y, b.z, b.w};
#pragma unroll
      for (int i = 0; i < 4; ++i)
#pragma unroll
        for (int j = 0; j < 4; ++j) acc[i][j] = fmaf(aa[i], bb[j], acc[i][j]);
    }
    __syncthreads();
  }
  float4 bv = *(const float4*)&bo[n0 + tx * 4];
  float bb[4] = {bv.x, bv.y, bv.z, bv.w};
#pragma unroll
  for (int i = 0; i < 4; ++i) {
    int row = m0 + ty * 4 + i;
    if (row < NROWS)
      *(float4*)&out[(size_t)row * NDIM + n0 + tx * 4] =
          make_float4(acc[i][0] + bb[0], acc[i][1] + bb[1],
                      acc[i][2] + bb[2], acc[i][3] + bb[3]);
  }
}

// ---------------------------------------------------------------------------
// K3: pe attention. Block = (row, head-group hg, key-split ks).
// Phase A builds the pe tile via 4 sincos + rotation recurrence per lane,
// stores it TRANSPOSED (pe_t[slot][key], XOR-swizzled) and does the
// pe-logit MFMA. Phase C reads pe_t rows as vectorized ds_read_b128.
// pe slot layout: 0..31 sin_r | 32..63 cos_r | 64..95 sin_t | 96..127 cos_t
//                 | 128 rc | 129 th | 130..159 zero
// Fragment maps (gfx950): A m=lane&15 k=(lane>>4)*8+j; B n=lane&15 same k;
// D col=lane&15 row=(lane>>4)*4+reg.
// ---------------------------------------------------------------------------
__global__ __launch_bounds__(256) void attn_pe_k(
    const float* __restrict__ s_ws, const short* __restrict__ u_ws,
    const float* __restrict__ vb, const float* __restrict__ pos,
    const float* __restrict__ Wv, const float* __restrict__ freqs,
    float* __restrict__ part)
{
  __shared__ short u_s[16 * USTR];
  __shared__ short p_bf[16 * PSTR];
  __shared__ short pe_t[160 * PTSTR];
  __shared__ float p_s[4][64];
  __shared__ float s_l[4][64];
  __shared__ float s_pe[4][64];
  __shared__ float w_s[4][160];
  __shared__ float rc_s[128], th_s[128];
  __shared__ float frp_s[NFREQ];
  __shared__ float m_s[4], l_s[4], fac_s[4];

  const int row = blockIdx.x;
  const int hg  = blockIdx.y;
  const int ks  = blockIdx.z;
  const int b = row / NL;
  const int i = row - b * NL;
  const bool spatial = (i < NLS);
  const int t = threadIdx.x;
  const int lane = t & 63;
  const int wv = t >> 6;
  const int g = lane >> 4;
  const int lr = lane & 15;
  const int hbase = hg * 4;
  const int h4 = t >> 6;
  const int dd = t & 63;

  for (int idx = t; idx < 16 * USTR / 2; idx += 256) ((int*)u_s)[idx] = 0;
  for (int idx = t; idx < 16 * PSTR / 2; idx += 256) ((int*)p_bf)[idx] = 0;
  if (t < NFREQ) frp_s[t] = freqs[t] * PI_F;
  if (t < 4) { m_s[t] = -1e30f; l_s[t] = 0.f; }
  __syncthreads();

  float px = 0.f, py = 0.f;
  if (spatial) {
    float2 pv = *(const float2*)&pos[(size_t)(b * NLS + i) * 2];
    px = pv.x; py = pv.y;
  }
  if (spatial && t < 128) {
    int key = ks * 128 + t;
    float2 kp = *(const float2*)&pos[(size_t)(b * NLS + key) * 2];
    float dx = kp.x - px, dy = kp.y - py;
    float r = sqrtf(dx * dx + dy * dy + 1e-8f);
    rc_s[t] = r / (PHYS_SCALE + r);
    th_s[t] = atan2f(dy, dx) * (1.0f / PI_F);
  }
  if (spatial) {
    for (int idx = t; idx < 4 * POSD; idx += 256) {
      int hh = idx / POSD, f = idx - hh * POSD;
      int slot = (f < 64) ? f : (f == 64) ? 128 : (f == 129) ? 129 : f - 1;
      u_s[hh * USTR + slot] =
          u_ws[((size_t)((hbase + hh) * NB + b) * SROWS + i) * UCOLS + f];
    }
  }
  __syncthreads();

  float oA = 0.f, oB = 0.f;
  f32x4 wacc[3];
#pragma unroll
  for (int q = 0; q < 3; ++q) wacc[q] = (f32x4){0.f, 0.f, 0.f, 0.f};

  for (int ti = 0; ti < 2; ++ti) {
    const int kloc = ks * 128 + ti * 64;   // key index 0..255
    const int koff = ti * 64;              // offset into rc_s/th_s

    // phase A: load base logits + build pe tile (recurrence) + pe-logit MFMA
    //          + transposed swizzled store to pe_t
    s_l[h4][dd] =
        s_ws[((size_t)((hbase + h4) * NB + b) * SROWS + i) * SCOLS + kloc + dd];
    if (spatial) {
      const int krow = wv * 16 + lr;       // local key 0..63
      const float rc = rc_s[koff + krow], th = th_s[koff + krow];
      const float f0 = frp_s[g * 8];
      const float dphi = frp_s[1] - frp_s[0];
      float sr, cr, st_, ct_;
      __sincosf(rc * f0, &sr, &cr);
      __sincosf(th * f0, &st_, &ct_);
      float srd, crd, std_, ctd;
      __sincosf(rc * dphi, &srd, &crd);
      __sincosf(th * dphi, &std_, &ctd);
      s16x8 a0, a1, a2, a3, a4;
#pragma unroll
      for (int j = 0; j < 8; ++j) {
        a0[j] = bfb(sr); a1[j] = bfb(cr); a2[j] = bfb(st_); a3[j] = bfb(ct_);
        a4[j] = 0;
        float nsr = fmaf(sr, crd, cr * srd);
        float ncr = fmaf(cr, crd, -sr * srd);
        sr = nsr; cr = ncr;
        float nst = fmaf(st_, ctd, ct_ * std_);
        float nct = fmaf(ct_, ctd, -st_ * std_);
        st_ = nst; ct_ = nct;
      }
      if (g == 0) { a4[0] = bfb(rc); a4[1] = bfb(th); }
      // transposed swizzled store: pe_t[s][krow ^ swz(s)]
#pragma unroll
      for (int jj = 0; jj < 8; ++jj) {
        const int s0 = g * 8 + jj;
        pe_t[(s0      ) * PTSTR + (krow ^ ((((s0      ) >> 3) & 3) << 4))] = a0[jj];
        pe_t[(s0 + 32 ) * PTSTR + (krow ^ ((((s0 + 32 ) >> 3) & 3) << 4))] = a1[jj];
        pe_t[(s0 + 64 ) * PTSTR + (krow ^ ((((s0 + 64 ) >> 3) & 3) << 4))] = a2[jj];
        pe_t[(s0 + 96 ) * PTSTR + (krow ^ ((((s0 + 96 ) >> 3) & 3) << 4))] = a3[jj];
        pe_t[(s0 + 128) * PTSTR + (krow ^ ((((s0 + 128) >> 3) & 3) << 4))] = a4[jj];
      }
      const short* ur = &u_s[lr * USTR + g * 8];
      f32x4 acc = (f32x4){0.f, 0.f, 0.f, 0.f};
      acc = __builtin_amdgcn_mfma_f32_16x16x32_bf16(a0, *(const s16x8*)(ur), acc, 0, 0, 0);
      acc = __builtin_amdgcn_mfma_f32_16x16x32_bf16(a1, *(const s16x8*)(ur + 32), acc, 0, 0, 0);
      acc = __builtin_amdgcn_mfma_f32_16x16x32_bf16(a2, *(const s16x8*)(ur + 64), acc, 0, 0, 0);
      acc = __builtin_amdgcn_mfma_f32_16x16x32_bf16(a3, *(const s16x8*)(ur + 96), acc, 0, 0, 0);
      acc = __builtin_amdgcn_mfma_f32_16x16x32_bf16(a4, *(const s16x8*)(ur + 128), acc, 0, 0, 0);
      if (lr < 4) {
#pragma unroll
        for (int r = 0; r < 4; ++r)
          s_pe[lr][wv * 16 + g * 4 + r] = acc[r] * ATTN_SCALE;
      }
    }
    __syncthreads();

    // phase B: online softmax (wave per head)
    {
      float v = s_l[h4][dd];
      if (spatial) v += s_pe[h4][dd];
      float mx = v;
#pragma unroll
      for (int off = 32; off > 0; off >>= 1)
        mx = fmaxf(mx, __shfl_xor(mx, off, 64));
      float m_old = m_s[h4];
      float m_new = fmaxf(m_old, mx);
      float p = __expf(v - m_new);
      p_s[h4][dd] = p;
      p_bf[h4 * PSTR + dd] = bfb(p);
      float sum = p;
#pragma unroll
      for (int off = 32; off > 0; off >>= 1)
        sum += __shfl_xor(sum, off, 64);
      if (lane == 0) {
        float fac = __expf(m_old - m_new);
        m_s[h4] = m_new;
        l_s[h4] = l_s[h4] * fac + sum;
        fac_s[h4] = fac;
      }
    }
    __syncthreads();

    // phase C: PV + w-accum MFMA (pe_t rows read as ds_read_b128)
    {
      float fac = fac_s[h4];
      oA *= fac; oB *= fac;
      const float* vbase = &vb[(size_t)(b * NL + kloc) * NDIM + (hbase + h4) * DHEAD + dd];
      const float* pp = p_s[h4];
#pragma unroll 8
      for (int j = 0; j < 64; j += 2) {
        oA = fmaf(pp[j], vbase[(size_t)j * NDIM], oA);
        oB = fmaf(pp[j + 1], vbase[(size_t)(j + 1) * NDIM], oB);
      }
    }
    if (spatial) {
      const float facw = fac_s[lr & 3];
#pragma unroll
      for (int q = 0; q < 3; ++q) {
        const int mc = wv + q * 4;
        if (mc < 10) {
#pragma unroll
          for (int r = 0; r < 4; ++r) wacc[q][r] *= facw;
          const int s = mc * 16 + lr;            // slot 0..159
          const int swz = ((s >> 3) & 3) << 4;
#pragma unroll
          for (int kc = 0; kc < 2; ++kc) {
            const int base = (kc * 32 + g * 8) ^ swz;
            const s16x8 a = *(const s16x8*)&pe_t[s * PTSTR + base];
            const s16x8 pb = *(const s16x8*)&p_bf[lr * PSTR + kc * 32 + g * 8];
            wacc[q] = __builtin_amdgcn_mfma_f32_16x16x32_bf16(a, pb, wacc[q], 0, 0, 0);
          }
        }
      }
    }
    __syncthreads();
  }

  // ---- tail (ks==1): 16 global keys, no pe ----
  if (ks == 1) {
    if (t < 64) {
      const int hh = t >> 4, j = t & 15;
      s_l[hh][j] =
          s_ws[((size_t)((hbase + hh) * NB + b) * SROWS + i) * SCOLS + 256 + j];
    }
    __syncthreads();
    {
      float v = (dd < 16) ? s_l[h4][dd] : -1e30f;
      float mx = v;
#pragma unroll
      for (int off = 32; off > 0; off >>= 1)
        mx = fmaxf(mx, __shfl_xor(mx, off, 64));
      float m_old = m_s[h4];
      float m_new = fmaxf(m_old, mx);
      float p = (dd < 16) ? __expf(v - m_new) : 0.f;
      if (dd < 16) p_s[h4][dd] = p;
      float sum = p;
#pragma unroll
      for (int off = 32; off > 0; off >>= 1)
        sum += __shfl_xor(sum, off, 64);
      if (lane == 0) {
        float fac = __expf(m_old - m_new);
        m_s[h4] = m_new;
        l_s[h4] = l_s[h4] * fac + sum;
        fac_s[h4] = fac;
      }
    }
    __syncthreads();
    {
      float fac = fac_s[h4];
      oA *= fac; oB *= fac;
      const float* vbase = &vb[(size_t)(b * NL + 256) * NDIM + (hbase + h4) * DHEAD + dd];
      const float* pp = p_s[h4];
#pragma unroll 4
      for (int j = 0; j < 16; j += 2) {
        oA = fmaf(pp[j], vbase[(size_t)j * NDIM], oA);
        oB = fmaf(pp[j + 1], vbase[(size_t)(j + 1) * NDIM], oB);
      }
    }
    if (spatial) {
      const float facw = fac_s[lr & 3];
#pragma unroll
      for (int q = 0; q < 3; ++q)
#pragma unroll
        for (int r = 0; r < 4; ++r) wacc[q][r] *= facw;
    }
  }

  // ---- epilogue: gather w, project with Wv_pe, write partial ----
  __syncthreads();
  if (spatial && lr < 4) {
#pragma unroll
    for (int q = 0; q < 3; ++q) {
      const int mc = wv + q * 4;
      if (mc < 10) {
#pragma unroll
        for (int r = 0; r < 4; ++r)
          w_s[lr][mc * 16 + g * 4 + r] = wacc[q][r];
      }
    }
  }
  __syncthreads();

  float o = oA + oB;
  if (spatial) {
    const float* wsr = w_s[h4];
    const float* wvb = &Wv[(size_t)512 * NDIM + (hbase + h4) * DHEAD + dd];
    float e0 = 0.f, e1 = 0.f;
#pragma unroll 4
    for (int sf = 0; sf < 64; sf += 2) {
      e0 = fmaf(wsr[sf], wvb[(size_t)sf * NDIM], e0);
      e1 = fmaf(wsr[sf + 1], wvb[(size_t)(sf + 1) * NDIM], e1);
    }
#pragma unroll 4
    for (int sf = 64; sf < 128; sf += 2) {
      e0 = fmaf(wsr[sf], wvb[(size_t)(sf + 1) * NDIM], e0);
      e1 = fmaf(wsr[sf + 1], wvb[(size_t)(sf + 2) * NDIM], e1);
    }
    e0 = fmaf(wsr[128], wvb[(size_t)64 * NDIM], e0);
    e1 = fmaf(wsr[129], wvb[(size_t)129 * NDIM], e1);
    o += e0 + e1;
  }
  float* prow = part + ((size_t)(ks * NROWS + row) * 2 + hg) * PART_STRIDE;
  prow[t] = o;
  if (t < 4) { prow[256 + t] = m_s[t]; prow[260 + t] = l_s[t]; }
}

// ---------------------------------------------------------------------------
// K4: combine 2 key-split partials per (row, head-group)
// ---------------------------------------------------------------------------
__global__ __launch_bounds__(256) void combine_k(
    const float* __restrict__ part, float* __restrict__ ao)
{
  const int row = blockIdx.x;
  const int hg = blockIdx.y;
  const int t = threadIdx.x;
  const int h4 = t >> 6;

  const float* p0 = part + ((size_t)(0 * NROWS + row) * 2 + hg) * PART_STRIDE;
  const float* p1 = part + ((size_t)(1 * NROWS + row) * 2 + hg) * PART_STRIDE;
  float m0 = p0[256 + h4], m1 = p1[256 + h4];
  float M = fmaxf(m0, m1);
  float f0 = __expf(m0 - M), f1 = __expf(m1 - M);
  float L = p0[260 + h4] * f0 + p1[260 + h4] * f1;
  ao[(size_t)row * NDIM + hg * 256 + t] = (p0[t] * f0 + p1[t] * f1) / L;
}

// ---------------------------------------------------------------------------
extern "C" void kernel_launch(void* const* d_in, const int* in_sizes, int n_in,
                              void* d_out, int out_size, void* d_ws, size_t ws_size,
                              hipStream_t stream)
{
  (void)in_sizes; (void)n_in; (void)out_size; (void)ws_size;
  const float* x     = (const float*)d_in[0];
  const float* pos   = (const float*)d_in[1];
  const float* Wq    = (const float*)d_in[2];
  const float* Wk    = (const float*)d_in[3];
  const float* Wv    = (const float*)d_in[4];
  const float* Wo    = (const float*)d_in[5];
  const float* bo    = (const float*)d_in[6];
  const float* freqs = (const float*)d_in[7];

  float* ws = (float*)d_ws;
  float* qkv  = ws;                                      // [3][544][512]
  float* qb   = qkv;
  float* kb   = qkv + (size_t)NROWS * NDIM;
  float* vb   = qkv + (size_t)2 * NROWS * NDIM;
  float* ao   = qkv + (size_t)3 * NROWS * NDIM;          // [544][512]
  float* part = ao  + (size_t)NROWS * NDIM;              // [2][544][2][264]
  float* s_ws = part + (size_t)2 * NROWS * 2 * PART_STRIDE;  // [8][2][320][320]
  short* u_ws = (short*)(s_ws + (size_t)NHEADS * NB * SROWS * SCOLS); // [8][2][320][132] bf16

  qkv_gemm_k<<<dim3(9, 24), 256, 0, stream>>>(x, Wq, Wk, Wv, qkv);
  su_gemm_k<<<dim3(10, 8, 8), 256, 0, stream>>>(qb, kb, Wk, s_ws, u_ws);
  attn_pe_k<<<dim3(NROWS, 2, 2), 256, 0, stream>>>(s_ws, u_ws, vb, pos, Wv, freqs, part);
  combine_k<<<dim3(NROWS, 2), 256, 0, stream>>>(part, ao);
  out_gemm_k<<<dim3(9, 8), 256, 0, stream>>>(ao, Wo, bo, (float*)d_out);
}